// Round 1
// baseline (103.315 us; speedup 1.0000x reference)
//
#include <hip/hip_runtime.h>
#include <hip/hip_bf16.h>

#define NPTS 8192
#define NQRY 8192
#define KMAX 128
#define TILE 2048

// Wave-per-query fixed-radius search with ballot compaction.
// Block = 256 threads = 4 waves = 4 queries. Points staged in LDS tiles.
__global__ __launch_bounds__(256) void frs_main_kernel(
    const float* __restrict__ pts, const float* __restrict__ qrs,
    const float* __restrict__ rad,
    float* __restrict__ out_idx, float* __restrict__ out_dist,
    int* __restrict__ counts) {
  __shared__ float4 sp[TILE];  // x, y, z, |p|^2

  const int lane = threadIdx.x & 63;
  const int wid = threadIdx.x >> 6;
  const int q = blockIdx.x * 4 + wid;

  const float q0 = qrs[q * 3 + 0];
  const float q1 = qrs[q * 3 + 1];
  const float q2 = qrs[q * 3 + 2];
  const float r = rad[0];
  const float r2 = __fmul_rn(r, r);
  // qq = (q0*q0 + q1*q1) + q2*q2, exact np association, no FMA contraction
  const float qq = __fadd_rn(
      __fadd_rn(__fmul_rn(q0, q0), __fmul_rn(q1, q1)), __fmul_rn(q2, q2));

  const unsigned long long lanemask_lt = (1ull << lane) - 1ull;
  int count = 0;  // wave-uniform

  float* const oi = out_idx + (size_t)q * KMAX;
  float* const od = out_dist + (size_t)q * KMAX;

  for (int t0 = 0; t0 < NPTS; t0 += TILE) {
    __syncthreads();  // previous tile fully consumed
    for (int i = threadIdx.x; i < TILE; i += 256) {
      const int pi = t0 + i;
      const float x = pts[pi * 3 + 0];
      const float y = pts[pi * 3 + 1];
      const float z = pts[pi * 3 + 2];
      const float pp = __fadd_rn(
          __fadd_rn(__fmul_rn(x, x), __fmul_rn(y, y)), __fmul_rn(z, z));
      sp[i] = make_float4(x, y, z, pp);
    }
    __syncthreads();

    for (int j = lane; j < TILE; j += 64) {
      const float4 p = sp[j];
      // dot = (q0*px + q1*py) + q2*pz  (np matmul association, no FMA)
      const float dot = __fadd_rn(
          __fadd_rn(__fmul_rn(q0, p.x), __fmul_rn(q1, p.y)),
          __fmul_rn(q2, p.z));
      // d2 = (qq + pp) - 2*dot, clamped at 0
      float d2 = __fsub_rn(__fadd_rn(qq, p.w), __fmul_rn(2.0f, dot));
      d2 = fmaxf(d2, 0.0f);
      const bool hit = d2 <= r2;
      const unsigned long long m = __ballot(hit);
      if (hit) {
        const int pos = count + __popcll(m & lanemask_lt);
        if (pos < KMAX) {
          oi[pos] = (float)(t0 + j);
          od[pos] = d2;
        }
      }
      count += __popcll(m);
    }
  }

  // fill padding: idx = -1, dist = 0
  for (int s = count + lane; s < KMAX; s += 64) {
    oi[s] = -1.0f;
    od[s] = 0.0f;
  }
  if (lane == 0) counts[q] = count;
}

// Single-block exclusive prefix sum of 8192 counts -> row_splits[8193] (as float).
__global__ __launch_bounds__(1024) void frs_scan_kernel(
    const int* __restrict__ counts, float* __restrict__ row_splits) {
  const int t = threadIdx.x;
  const int base = t * 8;
  int c[8];
  int s = 0;
#pragma unroll
  for (int i = 0; i < 8; i++) {
    c[i] = counts[base + i];
    s += c[i];
  }
  const int lane = t & 63;
  const int wid = t >> 6;
  int incl = s;
#pragma unroll
  for (int off = 1; off < 64; off <<= 1) {
    const int v = __shfl_up(incl, off, 64);
    if (lane >= off) incl += v;
  }
  __shared__ int wpart[16];
  if (lane == 63) wpart[wid] = incl;
  __syncthreads();
  if (t == 0) {
    int run = 0;
    for (int i = 0; i < 16; i++) {
      const int v = wpart[i];
      wpart[i] = run;
      run += v;
    }
  }
  __syncthreads();
  const int excl = wpart[wid] + (incl - s);
  int run = excl;
#pragma unroll
  for (int i = 0; i < 8; i++) {
    row_splits[base + i] = (float)run;
    run += c[i];
  }
  if (t == 1023) row_splits[NQRY] = (float)run;
}

extern "C" void kernel_launch(void* const* d_in, const int* in_sizes, int n_in,
                              void* d_out, int out_size, void* d_ws, size_t ws_size,
                              hipStream_t stream) {
  const float* pts = (const float*)d_in[0];   // [N,3]
  const float* qrs = (const float*)d_in[1];   // [Q,3]
  const float* rad = (const float*)d_in[2];   // scalar

  float* out = (float*)d_out;
  float* out_idx = out;                                // [Q,K]
  float* row_splits = out + (size_t)NQRY * KMAX;       // [Q+1]
  float* out_dist = row_splits + (NQRY + 1);           // [Q,K]

  int* counts = (int*)d_ws;  // 8192 ints

  frs_main_kernel<<<NQRY / 4, 256, 0, stream>>>(pts, qrs, rad, out_idx,
                                                out_dist, counts);
  frs_scan_kernel<<<1, 1024, 0, stream>>>(counts, row_splits);
}